// Round 8
// baseline (98.614 us; speedup 1.0000x reference)
//
#include <hip/hip_runtime.h>

// Laplacian pyramid loss via linearity: pyr(p) - pyr(t) = pyr(p - t).
// R8: R7 wave-streaming, re-tuned for latency coverage (R7 was 27% occupancy,
// loads consumed one bookkeeping-op after issue):
//  - DH=8 -> 2x waves (L0: 7680 waves = full residency, 7.5/SIMD)
//  - prefetch distance 2 (q0..q3 row-pairs, fully unrolled loop -> static regs)
//  - L2 handled by stream kernel too (D=64 = one strip, both edges active);
//    tail is only L3+L4 (31 KB LDS, 256 thr).
// One wave = 64 down-cols x 8 down-rows. Lane j owns down col DB+j (cur cols
// 2dc,2dc+1 via float2). h: 3 shuffles/row; v-tap: rolling 5-row h window;
// up: rolling ex/ox + 2 shuffles per down row; lap from rolling cur regs.
// Edge reflect = lane-local selects (algebra verified R4-R7).

__device__ __forceinline__ int reflect_i(int m, int S) {
    if (m < 0) m = -m;
    if (m >= S) m = 2 * S - 2 - m;
    return m;
}

__device__ __forceinline__ void wg_barrier() {
    asm volatile("s_waitcnt lgkmcnt(0)" ::: "memory");
    __builtin_amdgcn_s_barrier();
}

template <int SZ, int ISL0, int DH, int NCS, int NRS>
__global__ __launch_bounds__(256)
void stream_kernel(const float* __restrict__ a, const float* __restrict__ b,
                   float* __restrict__ dwn, float* __restrict__ acc, float scale) {
    constexpr int S = SZ, D = SZ / 2;
    const int wid  = (blockIdx.x * 256 + threadIdx.x) >> 6;
    const int lane = threadIdx.x & 63;
    const int cs = wid % NCS;
    const int rs = (wid / NCS) % NRS;
    const int n  = wid / (NCS * NRS);

    int DB, relS, relE;
    if constexpr (SZ == 512) {
        DB   = cs == 0 ? 0 : cs == 1 ? 59 : cs == 2 ? 119 : cs == 3 ? 179 : 192;
        relS = cs == 0 ? 0 : cs == 4 ? 49 : 2;
        relE = cs == 4 ? 63 : cs == 0 ? 60 : 61;
    } else if constexpr (SZ == 256) {
        DB   = cs == 0 ? 0 : cs == 1 ? 59 : 64;
        relS = cs == 0 ? 0 : cs == 1 ? 2 : 57;
        relE = cs == 0 ? 60 : cs == 1 ? 61 : 63;
    } else {
        DB = 0; relS = 0; relE = 63;             // D=64: one strip, both edges
    }

    const bool leftE  = (DB == 0);
    const bool rightE = (DB + 63 == D - 1);
    const int dc = DB + lane;
    const bool ownL = (lane >= relS) && (lane <= relE);

    const float* pa = a + (size_t)n * S * S + 2 * dc;
    const float* pb = ISL0 ? (b + (size_t)n * S * S + 2 * dc) : nullptr;

    struct Row { float2 va, vb; };
    auto issue_row = [&](int r, Row& rr) {
        int gr = reflect_i(r, S);
        rr.va = *(const float2*)(pa + (size_t)gr * S);
        if constexpr (ISL0) rr.vb = *(const float2*)(pb + (size_t)gr * S);
    };
    auto val = [&](const Row& rr) -> float2 {
        if constexpr (ISL0) return float2{rr.va.x - rr.vb.x, rr.va.y - rr.vb.y};
        else return rr.va;
    };
    auto hof = [&](float2 c) -> float {
        float cLx = __shfl_up(c.x, 1, 64);
        float cLy = __shfl_up(c.y, 1, 64);
        float cRx = __shfl_down(c.x, 1, 64);
        float h = cLx + 4.f * cLy + 6.f * c.x + 4.f * c.y + cRx;
        if (leftE && lane == 0)   h = 6.f * c.x + 8.f * c.y + 2.f * cRx;
        if (rightE && lane == 63) h = cLx + 4.f * cLy + 7.f * c.x + 4.f * c.y;
        return h;
    };

    const int R0 = rs * DH;
    const int rbase = 2 * R0 - 4;   // cur row of cA at m = R0-1

    Row r0, r1, r2, r3, r4, q0, q1, q2, q3;
    issue_row(rbase + 0, r0); issue_row(rbase + 1, r1); issue_row(rbase + 2, r2);
    issue_row(rbase + 3, r3); issue_row(rbase + 4, r4);
    issue_row(2 * R0 + 1, q0); issue_row(2 * R0 + 2, q1);  // consume @ it=0
    issue_row(2 * R0 + 3, q2); issue_row(2 * R0 + 4, q3);  // consume @ it=1

    float2 cA = val(r0), cB = val(r1), cC = val(r2), cD = val(r3), cE = val(r4);
    float hA = hof(cA), hB = hof(cB), hC = hof(cC), hD = hof(cD), hE = hof(cE);

    float ex0 = 0.f, ex1 = 0.f, ox0 = 0.f, ox1 = 0.f;
    float sum = 0.f;
    float* dptr = dwn + (size_t)n * D * D + dc;

    #pragma unroll
    for (int it = 0; it < DH + 2; ++it) {
        const int m = R0 - 1 + it;
        // down row m <- h rows (cur 2m-2..2m+2), /256
        float d = (hA + 4.f * hB + 6.f * hC + 4.f * hD + hE) * (1.f / 256.f);
        float dl = __shfl_up(d, 1, 64);
        float dr = __shfl_down(d, 1, 64);
        if (leftE && lane == 0)   dl = dr;   // down col -1 -> 1
        if (rightE && lane == 63) dr = d;    // down col D  -> D-1
        float ex2 = 0.125f * (dl + 6.f * d + dr);  // up @ even cur col 2dc
        float ox2 = 0.5f  * (d + dr);              // up @ odd  cur col 2dc+1

        if (it >= 1 && it <= DH && ownL)
            dptr[(size_t)m * D] = d;

        if (it >= 2) {                       // emit lap rows 2me, 2me+1
            const int me = m - 1;
            float eA = (me == 0) ? ex2 : ex0;       // down row -1 -> 1
            float oA = (me == 0) ? ox2 : ox0;
            float eC = (me == D - 1) ? ex1 : ex2;   // down row D -> D-1
            float oC = (me == D - 1) ? ox1 : ox2;
            float uee = 0.125f * (eA + 6.f * ex1 + eC);
            float ueo = 0.125f * (oA + 6.f * ox1 + oC);
            float uoe = 0.5f * (ex1 + eC);
            float uoo = 0.5f * (ox1 + oC);
            if (ownL)
                sum += fabsf(cA.x - uee) + fabsf(cA.y - ueo)
                     + fabsf(cB.x - uoe) + fabsf(cB.y - uoo);
        }
        ex0 = ex1; ex1 = ex2; ox0 = ox1; ox1 = ox2;
        cA = cC; cB = cD; cC = cE;
        hA = hC; hB = hD; hC = hE;
        if (it < DH + 1) {
            // consume prefetched rows 2m+3, 2m+4 (issued 2 iterations ago)
            if ((it & 1) == 0) {
                cD = val(q0); hD = hof(cD);
                cE = val(q1); hE = hof(cE);
                if (it < DH - 1) { issue_row(2 * m + 7, q0); issue_row(2 * m + 8, q1); }
            } else {
                cD = val(q2); hD = hof(cD);
                cE = val(q3); hE = hof(cE);
                if (it < DH - 1) { issue_row(2 * m + 7, q2); issue_row(2 * m + 8, q3); }
            }
        }
    }

    #pragma unroll
    for (int o = 32; o > 0; o >>= 1) sum += __shfl_down(sum, o, 64);
    if (lane == 0) atomicAdd(&acc[wid & 63], sum * scale);
}

// ---- in-LDS level (tail): cur (SxS resident) -> dn (DxD); returns partial
// sum of |cur - up(dn)|. Reflect = plain index math.
__device__ float level_in_lds(const float* cur, float* h, float* dn,
                              int S, int tid, int nt) {
    const int D = S >> 1;
    for (int i = tid; i < S * D; i += nt) {
        int r = i / D, xh = i % D;
        int c0 = reflect_i(2 * xh - 2, S), c1 = reflect_i(2 * xh - 1, S);
        int c3 = 2 * xh + 1, c4 = reflect_i(2 * xh + 2, S);
        const float* row = cur + r * S;
        h[i] = row[c0] + 4.f * row[c1] + 6.f * row[2 * xh] + 4.f * row[c3] + row[c4];
    }
    wg_barrier();
    for (int i = tid; i < D * D; i += nt) {
        int yh = i / D, xh = i % D;
        int r0 = reflect_i(2 * yh - 2, S), r1 = reflect_i(2 * yh - 1, S);
        int r3 = 2 * yh + 1, r4 = reflect_i(2 * yh + 2, S);
        dn[i] = (h[r0 * D + xh] + 4.f * h[r1 * D + xh] + 6.f * h[2 * yh * D + xh]
               + 4.f * h[r3 * D + xh] + h[r4 * D + xh]) * (1.f / 256.f);
    }
    wg_barrier();
    float sum = 0.f;
    for (int i = tid; i < D * D; i += nt) {
        int yh2 = i / D, q = i % D;
        int rm = (yh2 == 0) ? 1 : yh2 - 1;
        int rp = (yh2 == D - 1) ? D - 1 : yh2 + 1;
        int cm = (q == 0) ? 1 : q - 1;
        int cp = (q == D - 1) ? D - 1 : q + 1;
        float A00 = dn[rm * D + cm], A01 = dn[rm * D + q], A02 = dn[rm * D + cp];
        float A10 = dn[yh2 * D + cm], A11 = dn[yh2 * D + q], A12 = dn[yh2 * D + cp];
        float A20 = dn[rp * D + cm], A21 = dn[rp * D + q], A22 = dn[rp * D + cp];
        float ex0 = (A00 + 6.f * A01 + A02) * 0.125f;
        float ex1 = (A10 + 6.f * A11 + A12) * 0.125f;
        float ex2 = (A20 + 6.f * A21 + A22) * 0.125f;
        float ox0 = (A01 + A02) * 0.5f;
        float ox1 = (A11 + A12) * 0.5f;
        float ox2 = (A21 + A22) * 0.5f;
        float uee = (ex0 + 6.f * ex1 + ex2) * 0.125f;
        float ueo = (ox0 + 6.f * ox1 + ox2) * 0.125f;
        float uoe = (ex1 + ex2) * 0.5f;
        float uoo = (ox1 + ox2) * 0.5f;
        const float* c0 = cur + (2 * yh2) * S + 2 * q;
        sum += fabsf(c0[0] - uee) + fabsf(c0[1] - ueo)
             + fabsf(c0[S] - uoe) + fabsf(c0[S + 1] - uoo);
    }
    wg_barrier();
    return sum;
}

// levels 3+4 for one image per block: down2 (64x64) resident in LDS.
__global__ __launch_bounds__(256)
void tail_kernel(const float* __restrict__ d2, float* __restrict__ acc,
                 float s3, float s4) {
    __shared__ float cur[64 * 64];
    __shared__ float hbuf[64 * 32];
    __shared__ float dn3[32 * 32];
    __shared__ float dn4[16 * 16];
    int n = blockIdx.x, tid = threadIdx.x;
    const float4* src = (const float4*)(d2 + (size_t)n * 64 * 64);
    for (int i = tid; i < 64 * 16; i += 256) ((float4*)cur)[i] = src[i];
    wg_barrier();
    float sum = level_in_lds(cur, hbuf, dn3, 64, tid, 256) * s3;
    sum += level_in_lds(dn3, hbuf, dn4, 32, tid, 256) * s4;
    #pragma unroll
    for (int o = 32; o > 0; o >>= 1) sum += __shfl_down(sum, o, 64);
    __shared__ float s[4];
    int lane = tid & 63, w = tid >> 6;
    if (lane == 0) s[w] = sum;
    wg_barrier();
    if (tid == 0) atomicAdd(&acc[n & 63], s[0] + s[1] + s[2] + s[3]);
}

__global__ void finish_kernel(const float* __restrict__ acc, float* __restrict__ out) {
    float v = acc[threadIdx.x];
    #pragma unroll
    for (int o = 32; o > 0; o >>= 1) v += __shfl_down(v, o, 64);
    if (threadIdx.x == 0) out[0] = v;
}

extern "C" void kernel_launch(void* const* d_in, const int* in_sizes, int n_in,
                              void* d_out, int out_size, void* d_ws, size_t ws_size,
                              hipStream_t stream) {
    const float* p = (const float*)d_in[0];
    const float* t = (const float*)d_in[1];
    float* out = (float*)d_out;
    float* acc = (float*)d_ws;                    // 64 accumulator slots
    float* dn0 = acc + 64;                        // 48 * 256 * 256
    float* dn1 = dn0 + (size_t)48 * 256 * 256;    // 48 * 128 * 128
    float* dn2 = dn1 + (size_t)48 * 128 * 128;    // 48 * 64 * 64

    hipMemsetAsync(acc, 0, 64 * sizeof(float), stream);

    const int N = 48;  // 16 batch * 3 channels (depthwise)

    // L0: D=256: 5 col strips x 32 row strips x 48 = 7680 waves (1920 blocks)
    stream_kernel<512, 1, 8, 5, 32><<<1920, 256, 0, stream>>>(
        p, t, dn0, acc, 1.f / (float)(N * 512 * 512));
    // L1: D=128: 3 x 16 x 48 = 2304 waves (576 blocks)
    stream_kernel<256, 0, 8, 3, 16><<<576, 256, 0, stream>>>(
        dn0, nullptr, dn1, acc, 2.f / (float)(N * 256 * 256));
    // L2: D=64: 1 x 8 x 48 = 384 waves (96 blocks)
    stream_kernel<128, 0, 8, 1, 8><<<96, 256, 0, stream>>>(
        dn1, nullptr, dn2, acc, 4.f / (float)(N * 128 * 128));
    // L3+L4: one block per image, LDS-resident
    tail_kernel<<<N, 256, 0, stream>>>(dn2, acc,
                                       8.f / (float)(N * 64 * 64),
                                       16.f / (float)(N * 32 * 32));
    finish_kernel<<<1, 64, 0, stream>>>(acc, out);
}

// Round 9
// 62.681 us; speedup vs baseline: 1.5733x; 1.5733x over previous
//
#include <hip/hip_runtime.h>

// Laplacian pyramid loss via linearity: pyr(p) - pyr(t) = pyr(p - t).
// R9: async-LDS ring streaming. One wave (64-thread block) owns a full-width
// band of DH down-rows. Cur rows stream through a per-wave 8-row LDS ring via
// global_load_lds_dwordx4 (1KB contiguous/instr, no VGPR round-trip, deep
// in-flight) with counted s_waitcnt vmcnt(N) (never 0 in-loop) — R5-R8 all
// capped at ~1.5-2.3 TB/s effective because register-pipelined loads bound
// bytes-in-flight. Compute = R7's verified register algebra (h 5-tap, rolling
// v-tap, rolling ex/ox up-interp, lane-local edge reflect selects), full-width
// so zero column halos / ownership masks. L0 LDS reads are XOR-swizzled
// (stage pre-swizzles the GLOBAL source; ds_reads apply the same involution)
// to break 32B-stride b128 bank aliasing. Tail (L3+L4) + finish from R8.

__device__ __forceinline__ int reflect_i(int m, int S) {
    if (m < 0) m = -m;
    if (m >= S) m = 2 * S - 2 - m;
    return m;
}

__device__ __forceinline__ void wg_barrier() {
    asm volatile("s_waitcnt lgkmcnt(0)" ::: "memory");
    __builtin_amdgcn_s_barrier();
}

#define WAITVM(N) asm volatile("s_waitcnt vmcnt(" #N ")" ::: "memory")
#define WAITLGKM0 asm volatile("s_waitcnt lgkmcnt(0)" ::: "memory")

__device__ __forceinline__ void gld16(const void* g, void* l) {
    __builtin_amdgcn_global_load_lds(
        (const __attribute__((address_space(1))) void*)g,
        (__attribute__((address_space(3))) void*)l, 16, 0, 0);
}

// XOR-swizzle within a 2KB row slot (involution; 16B units; spreads the
// 32B-lane-stride b128 reads over all 8 bank groups). Identity for cpl<4.
template <int CPL>
__device__ __forceinline__ int swz(int B) {
    if constexpr (CPL == 4) return B ^ (((B >> 7) & 7) << 4);
    else return B;
}

template <int S, int ISL0, int DH>
__global__ __launch_bounds__(64)
void pyr_kernel(const float* __restrict__ a, const float* __restrict__ b,
                float* __restrict__ dwn, float* __restrict__ acc, float scale) {
    constexpr int D = S / 2;
    constexpr int CPL = S / 128;       // down cols per lane (4/2/1)
    constexpr int W = 2 * CPL + 3;     // cur window floats per lane
    constexpr int ROWB = (CPL == 1) ? 1024 : S * 4;  // ring slot bytes
    constexpr int NRING = 8;

    __shared__ float4 ringmem[(NRING * ROWB * (ISL0 ? 2 : 1)) / 16];
    char* ra = (char*)ringmem;
    char* rb = ra + NRING * ROWB;      // t-ring (L0 only)

    const int lane = threadIdx.x;
    const int bid = blockIdx.x;
    constexpr int NRS = D / DH;
    const int rs = bid % NRS;
    const int n = bid / NRS;
    const int R0 = rs * DH;
    const size_t gbase = (size_t)n * S * S;

    auto stage_row = [&](int s) {
        int gr = reflect_i(2 * R0 - 4 + s, S);
        const char* ga = (const char*)(a + gbase + (size_t)gr * S);
        char* la = ra + (s & 7) * ROWB;
        if constexpr (CPL == 4) {
            gld16(ga + swz<CPL>(16 * lane), la);
            gld16(ga + swz<CPL>(16 * lane + 1024), la + 1024);
        } else if constexpr (CPL == 2) {
            gld16(ga + 16 * lane, la);
        } else {
            gld16(ga + 16 * (lane & 31), la);   // 512B row, lanes>=32 dup to pad
        }
        if constexpr (ISL0) {
            const char* gb = (const char*)(b + gbase + (size_t)gr * S);
            char* lb = rb + (s & 7) * ROWB;
            gld16(gb + swz<CPL>(16 * lane), lb);
            gld16(gb + swz<CPL>(16 * lane + 1024), lb + 1024);
        }
    };

    // read the 5-tap cur window (cols 2*CPL*lane-2 .. +2*CPL) for row seq s
    auto read_win = [&](int s, float* w) {
        const char* pa = ra + (s & 7) * ROWB;
        if constexpr (CPL == 4) {
            int bl = 32 * lane;
            float2 lo = *(const float2*)(pa + swz<CPL>(lane ? bl - 8 : 0));
            float4 m0 = *(const float4*)(pa + swz<CPL>(bl));
            float4 m1 = *(const float4*)(pa + swz<CPL>(bl + 16));
            float hi = *(const float*)(pa + swz<CPL>(lane == 63 ? 2032 : bl + 32));
            w[0]=lo.x; w[1]=lo.y; w[2]=m0.x; w[3]=m0.y; w[4]=m0.z; w[5]=m0.w;
            w[6]=m1.x; w[7]=m1.y; w[8]=m1.z; w[9]=m1.w; w[10]=hi;
            if constexpr (ISL0) {
                const char* pb = rb + (s & 7) * ROWB;
                float2 l2 = *(const float2*)(pb + swz<CPL>(lane ? bl - 8 : 0));
                float4 t0 = *(const float4*)(pb + swz<CPL>(bl));
                float4 t1 = *(const float4*)(pb + swz<CPL>(bl + 16));
                float h2 = *(const float*)(pb + swz<CPL>(lane == 63 ? 2032 : bl + 32));
                w[0]-=l2.x; w[1]-=l2.y; w[2]-=t0.x; w[3]-=t0.y; w[4]-=t0.z;
                w[5]-=t0.w; w[6]-=t1.x; w[7]-=t1.y; w[8]-=t1.z; w[9]-=t1.w; w[10]-=h2;
            }
        } else if constexpr (CPL == 2) {
            int bl = 16 * lane;
            float2 lo = *(const float2*)(pa + (lane ? bl - 8 : 0));
            float4 m0 = *(const float4*)(pa + bl);
            float hi = *(const float*)(pa + (lane == 63 ? 1008 : bl + 16));
            w[0]=lo.x; w[1]=lo.y; w[2]=m0.x; w[3]=m0.y; w[4]=m0.z; w[5]=m0.w; w[6]=hi;
        } else {
            int bl = 8 * lane;
            float2 lo = *(const float2*)(pa + (lane ? bl - 8 : 0));
            float2 m0 = *(const float2*)(pa + bl);
            float hi = *(const float*)(pa + (lane == 63 ? 496 : bl + 8));
            w[0]=lo.x; w[1]=lo.y; w[2]=m0.x; w[3]=m0.y; w[4]=hi;
        }
        // image-edge reflect: col -2 -> 2 (k=4), col -1 -> 1 (k=3), col S -> S-2 (k=W-3)
        if (lane == 0)  { w[0] = w[4]; w[1] = w[3]; }
        if (lane == 63) { w[W - 1] = w[W - 3]; }
    };

    auto read_cur = [&](int s, float* c) {   // in-lane cur cols only (2*CPL)
        const char* pa = ra + (s & 7) * ROWB;
        if constexpr (CPL == 4) {
            int bl = 32 * lane;
            float4 x = *(const float4*)(pa + swz<CPL>(bl));
            float4 y = *(const float4*)(pa + swz<CPL>(bl + 16));
            c[0]=x.x; c[1]=x.y; c[2]=x.z; c[3]=x.w; c[4]=y.x; c[5]=y.y; c[6]=y.z; c[7]=y.w;
            if constexpr (ISL0) {
                const char* pb = rb + (s & 7) * ROWB;
                float4 u = *(const float4*)(pb + swz<CPL>(bl));
                float4 v = *(const float4*)(pb + swz<CPL>(bl + 16));
                c[0]-=u.x; c[1]-=u.y; c[2]-=u.z; c[3]-=u.w;
                c[4]-=v.x; c[5]-=v.y; c[6]-=v.z; c[7]-=v.w;
            }
        } else if constexpr (CPL == 2) {
            float4 x = *(const float4*)(pa + 16 * lane);
            c[0]=x.x; c[1]=x.y; c[2]=x.z; c[3]=x.w;
        } else {
            float2 x = *(const float2*)(pa + 8 * lane);
            c[0]=x.x; c[1]=x.y;
        }
    };

    auto hof = [&](const float* w, float* h) {
        #pragma unroll
        for (int j = 0; j < CPL; j++)
            h[j] = w[2*j] + 4.f*w[2*j+1] + 6.f*w[2*j+2] + 4.f*w[2*j+3] + w[2*j+4];
    };

    // prologue: fill ring (rows seq 0..7)
    #pragma unroll
    for (int s = 0; s < 8; ++s) stage_row(s);
    if constexpr (CPL == 4) { WAITVM(20); } else { WAITVM(5); }

    float hA[CPL], hB[CPL], hC[CPL], hD[CPL], hE[CPL];
    {
        float w[W];
        read_win(0, w); hof(w, hA);
        read_win(1, w); hof(w, hB);
        read_win(2, w); hof(w, hC);
    }
    float ex0[CPL] = {}, ex1[CPL] = {}, ex2[CPL], ox0[CPL] = {}, ox1[CPL] = {}, ox2[CPL];
    float sum = 0.f;
    float* dbase = dwn + (size_t)n * D * D;

    #pragma unroll
    for (int it = 0; it <= DH + 1; ++it) {
        const int m = R0 - 1 + it;
        if (it <= DH) {
            if constexpr (CPL == 4) { WAITVM(12); } else { WAITVM(3); }
        } else {
            WAITVM(0);
        }
        {
            float w[W];
            read_win(2 * it + 3, w); hof(w, hD);
            read_win(2 * it + 4, w); hof(w, hE);
        }
        float d[CPL], dl[CPL], dr[CPL];
        #pragma unroll
        for (int j = 0; j < CPL; j++)
            d[j] = (hA[j] + 4.f*hB[j] + 6.f*hC[j] + 4.f*hD[j] + hE[j]) * (1.f / 256.f);
        float dli = __shfl_up(d[CPL - 1], 1, 64);
        float dri = __shfl_down(d[0], 1, 64);
        dl[0] = (lane == 0) ? ((CPL > 1) ? d[1] : dri) : dli;   // col -1 -> 1
        #pragma unroll
        for (int j = 1; j < CPL; j++) dl[j] = d[j - 1];
        dr[CPL - 1] = (lane == 63) ? d[CPL - 1] : dri;          // col D -> D-1
        #pragma unroll
        for (int j = 0; j < CPL - 1; j++) dr[j] = d[j + 1];
        #pragma unroll
        for (int j = 0; j < CPL; j++) {
            ex2[j] = 0.125f * (dl[j] + 6.f * d[j] + dr[j]);
            ox2[j] = 0.5f * (d[j] + dr[j]);
        }

        if (it >= 1 && it <= DH) {
            char* dst = (char*)(dbase + (size_t)m * D + CPL * lane);
            if constexpr (CPL == 4)      *(float4*)dst = make_float4(d[0], d[1], d[2], d[3]);
            else if constexpr (CPL == 2) *(float2*)dst = make_float2(d[0], d[1]);
            else                         *(float*)dst = d[0];
        }

        if (it >= 2) {
            const int me = m - 1;
            float cA[2 * CPL], cB[2 * CPL];
            read_cur(2 * it, cA);
            read_cur(2 * it + 1, cB);
            #pragma unroll
            for (int j = 0; j < CPL; j++) {
                float eA = (me == 0) ? ex2[j] : ex0[j];       // down row -1 -> 1
                float oA = (me == 0) ? ox2[j] : ox0[j];
                float eC = (me == D - 1) ? ex1[j] : ex2[j];   // down row D -> D-1
                float oC = (me == D - 1) ? ox1[j] : ox2[j];
                float uee = 0.125f * (eA + 6.f * ex1[j] + eC);
                float ueo = 0.125f * (oA + 6.f * ox1[j] + oC);
                float uoe = 0.5f * (ex1[j] + eC);
                float uoo = 0.5f * (ox1[j] + oC);
                sum += fabsf(cA[2*j] - uee) + fabsf(cA[2*j+1] - ueo)
                     + fabsf(cB[2*j] - uoe) + fabsf(cB[2*j+1] - uoo);
            }
        }

        #pragma unroll
        for (int j = 0; j < CPL; j++) {
            ex0[j] = ex1[j]; ex1[j] = ex2[j];
            ox0[j] = ox1[j]; ox1[j] = ox2[j];
            hA[j] = hC[j]; hB[j] = hD[j]; hC[j] = hE[j];
        }

        if (it <= DH - 1) {
            WAITLGKM0;                       // slot reuse: lap reads done first
            stage_row(8 + 2 * it);
            stage_row(9 + 2 * it);
        }
    }

    #pragma unroll
    for (int o = 32; o > 0; o >>= 1) sum += __shfl_down(sum, o, 64);
    if (lane == 0) atomicAdd(&acc[bid & 63], sum * scale);
}

// ---- tail: levels 3+4 per image in LDS (proven R8) ----
__device__ float level_in_lds(const float* cur, float* h, float* dn,
                              int S, int tid, int nt) {
    const int D = S >> 1;
    for (int i = tid; i < S * D; i += nt) {
        int r = i / D, xh = i % D;
        int c0 = reflect_i(2 * xh - 2, S), c1 = reflect_i(2 * xh - 1, S);
        int c3 = 2 * xh + 1, c4 = reflect_i(2 * xh + 2, S);
        const float* row = cur + r * S;
        h[i] = row[c0] + 4.f * row[c1] + 6.f * row[2 * xh] + 4.f * row[c3] + row[c4];
    }
    wg_barrier();
    for (int i = tid; i < D * D; i += nt) {
        int yh = i / D, xh = i % D;
        int r0 = reflect_i(2 * yh - 2, S), r1 = reflect_i(2 * yh - 1, S);
        int r3 = 2 * yh + 1, r4 = reflect_i(2 * yh + 2, S);
        dn[i] = (h[r0 * D + xh] + 4.f * h[r1 * D + xh] + 6.f * h[2 * yh * D + xh]
               + 4.f * h[r3 * D + xh] + h[r4 * D + xh]) * (1.f / 256.f);
    }
    wg_barrier();
    float sum = 0.f;
    for (int i = tid; i < D * D; i += nt) {
        int yh2 = i / D, q = i % D;
        int rm = (yh2 == 0) ? 1 : yh2 - 1;
        int rp = (yh2 == D - 1) ? D - 1 : yh2 + 1;
        int cm = (q == 0) ? 1 : q - 1;
        int cp = (q == D - 1) ? D - 1 : q + 1;
        float A00 = dn[rm * D + cm], A01 = dn[rm * D + q], A02 = dn[rm * D + cp];
        float A10 = dn[yh2 * D + cm], A11 = dn[yh2 * D + q], A12 = dn[yh2 * D + cp];
        float A20 = dn[rp * D + cm], A21 = dn[rp * D + q], A22 = dn[rp * D + cp];
        float ex0 = (A00 + 6.f * A01 + A02) * 0.125f;
        float ex1 = (A10 + 6.f * A11 + A12) * 0.125f;
        float ex2 = (A20 + 6.f * A21 + A22) * 0.125f;
        float ox0 = (A01 + A02) * 0.5f;
        float ox1 = (A11 + A12) * 0.5f;
        float ox2 = (A21 + A22) * 0.5f;
        float uee = (ex0 + 6.f * ex1 + ex2) * 0.125f;
        float ueo = (ox0 + 6.f * ox1 + ox2) * 0.125f;
        float uoe = (ex1 + ex2) * 0.5f;
        float uoo = (ox1 + ox2) * 0.5f;
        const float* c0 = cur + (2 * yh2) * S + 2 * q;
        sum += fabsf(c0[0] - uee) + fabsf(c0[1] - ueo)
             + fabsf(c0[S] - uoe) + fabsf(c0[S + 1] - uoo);
    }
    wg_barrier();
    return sum;
}

__global__ __launch_bounds__(256)
void tail_kernel(const float* __restrict__ d2, float* __restrict__ acc,
                 float s3, float s4) {
    __shared__ float cur[64 * 64];
    __shared__ float hbuf[64 * 32];
    __shared__ float dn3[32 * 32];
    __shared__ float dn4[16 * 16];
    int n = blockIdx.x, tid = threadIdx.x;
    const float4* src = (const float4*)(d2 + (size_t)n * 64 * 64);
    for (int i = tid; i < 64 * 16; i += 256) ((float4*)cur)[i] = src[i];
    wg_barrier();
    float sum = level_in_lds(cur, hbuf, dn3, 64, tid, 256) * s3;
    sum += level_in_lds(dn3, hbuf, dn4, 32, tid, 256) * s4;
    #pragma unroll
    for (int o = 32; o > 0; o >>= 1) sum += __shfl_down(sum, o, 64);
    __shared__ float s[4];
    int lane = tid & 63, w = tid >> 6;
    if (lane == 0) s[w] = sum;
    wg_barrier();
    if (tid == 0) atomicAdd(&acc[n & 63], s[0] + s[1] + s[2] + s[3]);
}

__global__ void finish_kernel(const float* __restrict__ acc, float* __restrict__ out) {
    float v = acc[threadIdx.x];
    #pragma unroll
    for (int o = 32; o > 0; o >>= 1) v += __shfl_down(v, o, 64);
    if (threadIdx.x == 0) out[0] = v;
}

extern "C" void kernel_launch(void* const* d_in, const int* in_sizes, int n_in,
                              void* d_out, int out_size, void* d_ws, size_t ws_size,
                              hipStream_t stream) {
    const float* p = (const float*)d_in[0];
    const float* t = (const float*)d_in[1];
    float* out = (float*)d_out;
    float* acc = (float*)d_ws;                    // 64 accumulator slots
    float* dn0 = acc + 64;                        // 48 * 256 * 256
    float* dn1 = dn0 + (size_t)48 * 256 * 256;    // 48 * 128 * 128
    float* dn2 = dn1 + (size_t)48 * 128 * 128;    // 48 * 64 * 64

    hipMemsetAsync(acc, 0, 64 * sizeof(float), stream);

    const int N = 48;  // 16 batch * 3 channels (depthwise)

    // L0: 48 imgs x 16 row bands = 768 waves (1 wave/block, 3 blocks/CU)
    pyr_kernel<512, 1, 16><<<48 * 16, 64, 0, stream>>>(
        p, t, dn0, acc, 1.f / (float)(N * 512 * 512));
    // L1: 48 x 16 = 768 waves
    pyr_kernel<256, 0, 8><<<48 * 16, 64, 0, stream>>>(
        dn0, nullptr, dn1, acc, 2.f / (float)(N * 256 * 256));
    // L2: 48 x 16 = 768 waves
    pyr_kernel<128, 0, 4><<<48 * 16, 64, 0, stream>>>(
        dn1, nullptr, dn2, acc, 4.f / (float)(N * 128 * 128));
    // L3+L4: one block per image, LDS-resident
    tail_kernel<<<N, 256, 0, stream>>>(dn2, acc,
                                       8.f / (float)(N * 64 * 64),
                                       16.f / (float)(N * 32 * 32));
    finish_kernel<<<1, 64, 0, stream>>>(acc, out);
}